// Round 19
// baseline (1605.432 us; speedup 1.0000x reference)
//
#include <hip/hip_runtime.h>
#include <hip/hip_bf16.h>
#include <stdint.h>

using bf16 = __hip_bfloat16;
typedef __attribute__((ext_vector_type(8))) short short8;
typedef __attribute__((ext_vector_type(4))) float f32x4;

#define GLD16(gptr, lptr) \
  __builtin_amdgcn_global_load_lds((const __attribute__((address_space(1))) void*)(gptr), \
                                   (__attribute__((address_space(3))) void*)(lptr), 16, 0, 0)

__device__ __forceinline__ float b2f(bf16 h){ return __bfloat162float(h); }
__device__ __forceinline__ bf16  f2b(float f){ return __float2bfloat16(f); }
// tanh-approx GELU in exp form (identical math, 1 hw transcendental):
__device__ __forceinline__ float geluf(float x){
  float t2 = 1.5957691216057308f * (x + 0.044715f*x*x*x);
  return x / (1.0f + __expf(-t2));
}
__device__ __forceinline__ float wsum(float v){
  v += __shfl_xor(v,32); v += __shfl_xor(v,16); v += __shfl_xor(v,8);
  v += __shfl_xor(v,4);  v += __shfl_xor(v,2);  v += __shfl_xor(v,1);
  return v;
}

union BV { uint4 u; bf16 h[8]; };

// ---------------- bf16 MFMA GEMM:  C[M][N] = A[M][K] @ Bt[N][K]^T + bias ----------------
// r14 proven core (1606 us): 128x128 tile, BK=64, 4 waves, single-buffer LDS 34816 B ->
// 4 blocks/CU, drain-per-step sync, T2 XOR-swizzle via pre-swizzled global source.
// EPI: 0 = bias, 1 = bias+gelu, 2 = bias + residual add (in-place, tile-local),
//      3 = bias + FUSED CROSS-ATTENTION: the staged qh tile covers exactly 2 heads
//          (dh=64); each thread owns one (row, head): 4 scores from LDS row-segment,
//          softmax, V-accumulate from L2-resident kv (Res = kv base), direct write.
//          No new sync: all after the existing __syncthreads(). (attn math == attn_k.)
template<int EPI>
__global__ __launch_bounds__(256, 4)
void gemm_bt(const bf16* __restrict__ A, int lda,
             const bf16* __restrict__ Bt,
             const float* __restrict__ bias,
             bf16* __restrict__ C, int ldc, int K,
             const bf16* __restrict__ Res)
{
  // K-loop: [A 128x64 | B 128x64] = 32 KB; epilogue reuses as [128][136] = 34816 B
  __shared__ __align__(16) bf16 smem[17408];
  const int tid  = threadIdx.x;
  const int wave = tid >> 6;
  const int lane = tid & 63;

  const int nwg = gridDim.x * gridDim.y;
  int bid = blockIdx.x + gridDim.x * blockIdx.y;
  if ((nwg & 7) == 0) bid = (bid & 7) * (nwg >> 3) + (bid >> 3);
  const int bx = bid % gridDim.x;
  const int by = bid / gridDim.x;
  const long mBlk = (long)by * 128;
  const int  nBlk = bx * 128;
  const int wm = (wave >> 1) * 64;
  const int wn = (wave & 1)  * 64;

  // staging source (pre-swizzled): lane l fetches k-chunk j=(l&7)^(l>>3) of its row
  const int lr = lane >> 3;              // 0..7
  const int kc = ((lane & 7) ^ lr) << 3;
  const bf16* aS = A  + (mBlk + wave*32 + lr) * (long)lda + kc;
  const bf16* bS = Bt + (long)(nBlk + wave*32 + lr) * K   + kc;

  // fragment read geometry
  const int sA = lane >> 4;              // 0..3
  const int rA = wm + (lane & 15);
  const int rB = wn + (lane & 15);
  const int xA = rA & 7, xB = rB & 7;

  f32x4 acc[4][4];
  #pragma unroll
  for (int m=0;m<4;++m)
    #pragma unroll
    for (int n=0;n<4;++n)
      acc[m][n] = (f32x4){0.f,0.f,0.f,0.f};

  const int nt = K >> 6;
  for (int t = 0; t < nt; ++t) {
    {
      bf16* sAl = smem + wave*2048;
      bf16* sBl = smem + 8192 + wave*2048;
      const int ko = t*64;
      #pragma unroll
      for (int c=0;c<4;++c) {
        GLD16(aS + (long)c*8*lda + ko, sAl + c*512);
        GLD16(bS + (long)c*8*K   + ko, sBl + c*512);
      }
    }
    __syncthreads();   // drains vmcnt+lgkmcnt: tile landed, all waves ready
    #pragma unroll
    for (int ks=0; ks<2; ++ks) {
      const int j = (ks<<2) + sA;
      short8 af[4], bfv[4];
      #pragma unroll
      for (int m=0;m<4;++m)
        af[m]  = *(const short8*)&smem[(rA + m*16)*64 + ((j ^ xA) << 3)];
      #pragma unroll
      for (int n=0;n<4;++n)
        bfv[n] = *(const short8*)&smem[8192 + (rB + n*16)*64 + ((j ^ xB) << 3)];
      #pragma unroll
      for (int m=0;m<4;++m)
        #pragma unroll
        for (int n=0;n<4;++n)
          acc[m][n] = __builtin_amdgcn_mfma_f32_16x16x32_bf16(af[m], bfv[n], acc[m][n], 0, 0, 0);
    }
    __syncthreads();   // all reads done before next STAGE / epilogue overwrites
  }

  // ---- epilogue: bias(+gelu) -> LDS stage (padded rows) ----
  #pragma unroll
  for (int n=0;n<4;++n) {
    const int col = wn + n*16 + (lane & 15);
    float bi = bias[nBlk + col];
    #pragma unroll
    for (int m=0;m<4;++m) {
      #pragma unroll
      for (int j=0;j<4;++j) {
        float x = acc[m][n][j] + bi;
        if (EPI == 1) x = geluf(x);
        smem[(wm + m*16 + (lane>>4)*4 + j)*136 + col] = f2b(x);
      }
    }
  }
  __syncthreads();

  if (EPI == 3) {
    // ---- fused cross-attention (KV len 4): thread -> (row, local head) ----
    const int row = tid >> 1;            // 0..127
    const int lh  = tid & 1;             // local head within this tile's 2 heads
    const long grow = mBlk + row;
    const int b = (int)(grow / 96);
    const bf16* qrow = &smem[row*136 + lh*64];             // this (row,head)'s qh segment
    const bf16* kvb  = Res + (long)b*4096 + nBlk + lh*64;  // K base; +c*1024; V at +512
    float s[4];
    #pragma unroll
    for (int c=0;c<4;++c){
      const bf16* kcp = kvb + c*1024;
      float p = 0.f;
      #pragma unroll
      for (int k0=0;k0<64;k0+=8){
        BV q8, k8;
        q8.u = *(const uint4*)(qrow + k0);
        k8.u = *(const uint4*)(kcp + k0);
        #pragma unroll
        for (int j=0;j<8;++j) p += b2f(q8.h[j]) * b2f(k8.h[j]);
      }
      s[c] = p * 0.125f;
    }
    float mx = fmaxf(fmaxf(s[0],s[1]), fmaxf(s[2],s[3]));
    float e0=__expf(s[0]-mx), e1=__expf(s[1]-mx), e2=__expf(s[2]-mx), e3=__expf(s[3]-mx);
    float inv = 1.f/(e0+e1+e2+e3);
    float p4[4] = {e0*inv, e1*inv, e2*inv, e3*inv};
    #pragma unroll
    for (int k0=0;k0<64;k0+=8){
      float o8[8] = {0,0,0,0,0,0,0,0};
      #pragma unroll
      for (int c=0;c<4;++c){
        BV v8; v8.u = *(const uint4*)(kvb + c*1024 + 512 + k0);
        #pragma unroll
        for (int j=0;j<8;++j) o8[j] += p4[c]*b2f(v8.h[j]);
      }
      BV O;
      #pragma unroll
      for (int j=0;j<8;++j) O.h[j] = f2b(o8[j]);
      *(uint4*)&C[grow*(long)ldc + nBlk + lh*64 + k0] = O.u;
    }
  } else {
    // ---- coalesced uint4 stores (EPI 0/1/2) ----
    #pragma unroll
    for (int it=0; it<8; ++it) {
      int o = it*2048 + tid*8;
      int row = o >> 7, col = o & 127;
      uint4 v = *(const uint4*)&smem[row*136 + col];
      if (EPI == 2) {   // fused residual add
        uint4 r = *(const uint4*)&Res[(mBlk + row)*(long)ldc + nBlk + col];
        BV a, b, oo;
        a.u = v; b.u = r;
        #pragma unroll
        for (int j=0;j<8;++j) oo.h[j] = f2b(b2f(a.h[j]) + b2f(b.h[j]));
        v = oo.u;
      }
      *(uint4*)&C[(mBlk + row)*(long)ldc + nBlk + col] = v;
    }
  }
}

// ---------------- prep: fp32 W[K][N] -> bf16 Wt[N][K] (tiled transpose) ----------------
__global__ void transpose_w(const float* __restrict__ src, bf16* __restrict__ dst,
                            int N, long srcStride, long dstStride, int dstRowOff, int dstLd)
{
  __shared__ float t[32][33];
  src += (long)blockIdx.z * srcStride;
  dst += (long)blockIdx.z * dstStride;
  int n0 = blockIdx.x*32, k0 = blockIdx.y*32;
  int tx = threadIdx.x & 31, ty = threadIdx.x >> 5;
  #pragma unroll
  for (int r=0;r<4;++r) t[ty + r*8][tx] = src[(long)(k0+ty+r*8)*N + n0+tx];
  __syncthreads();
  #pragma unroll
  for (int r=0;r<4;++r)
    dst[(long)(dstRowOff + n0 + ty + r*8)*dstLd + k0 + tx] = f2b(t[tx][ty+r*8]);
}

__global__ void f32_to_bf16_k(const float* __restrict__ src, bf16* __restrict__ dst, long n)
{
  long i = ((long)blockIdx.x*256 + threadIdx.x) * 4;
  if (i + 3 < n) {
    float4 v = *(const float4*)(src + i);
    dst[i+0]=f2b(v.x); dst[i+1]=f2b(v.y); dst[i+2]=f2b(v.z); dst[i+3]=f2b(v.w);
  }
}

__global__ void concat2(float* __restrict__ dst, long dStride,
                        const float* __restrict__ a, long aStride, int na,
                        const float* __restrict__ b, long bStride, int nb)
{
  int z = blockIdx.y;
  int i = blockIdx.x*256 + threadIdx.x;
  if (i < na) dst[z*dStride + i] = a[z*aStride + i];
  else if (i < na + nb) dst[z*dStride + i] = b[z*bStride + (i - na)];
}

// q0[b][c*24+n][d] = view_emb[c][d] + kp_emb[n][d]
__global__ void init_q(const float* __restrict__ vw, const float* __restrict__ kp,
                       bf16* __restrict__ q)
{
  long gid = (long)blockIdx.x*256 + threadIdx.x;  // 512*96*64 total
  int b  = (int)(gid / 6144);
  int r  = (int)(gid % 6144);
  int cn = r >> 6;
  int d0 = (r & 63) * 8;
  int c = cn / 24, n = cn % 24;
  const float4* v4 = (const float4*)(vw + c*512 + d0);
  const float4* k4 = (const float4*)(kp + n*512 + d0);
  float4 va = v4[0], vb = v4[1], ka = k4[0], kb = k4[1];
  BV o;
  o.h[0]=f2b(va.x+ka.x); o.h[1]=f2b(va.y+ka.y); o.h[2]=f2b(va.z+ka.z); o.h[3]=f2b(va.w+ka.w);
  o.h[4]=f2b(vb.x+kb.x); o.h[5]=f2b(vb.y+kb.y); o.h[6]=f2b(vb.z+kb.z); o.h[7]=f2b(vb.w+kb.w);
  *(uint4*)(q + (long)b*49152 + cn*512 + d0) = o.u;
}

// q96[cn][d] = view_emb[c][d] + kp_emb[n][d]  (the 96 distinct pre-layer-1 rows)
__global__ void init_q96(const float* __restrict__ vw, const float* __restrict__ kp,
                         bf16* __restrict__ q96)
{
  int gid = blockIdx.x*256 + threadIdx.x;   // 96*64 = 6144 threads
  int cn = gid >> 6;
  int d0 = (gid & 63) * 8;
  int c = cn / 24, n = cn % 24;
  const float4* v4 = (const float4*)(vw + c*512 + d0);
  const float4* k4 = (const float4*)(kp + n*512 + d0);
  float4 va = v4[0], vb = v4[1], ka = k4[0], kb = k4[1];
  BV o;
  o.h[0]=f2b(va.x+ka.x); o.h[1]=f2b(va.y+ka.y); o.h[2]=f2b(va.z+ka.z); o.h[3]=f2b(va.w+ka.w);
  o.h[4]=f2b(vb.x+kb.x); o.h[5]=f2b(vb.y+kb.y); o.h[6]=f2b(vb.z+kb.z); o.h[7]=f2b(vb.w+kb.w);
  *(uint4*)(q96 + (long)cn*512 + d0) = o.u;
}

// q = LN(q) * g + b  in place  (wave per row of 512; residual already folded by gemm EPI=2)
__global__ void ln_only(bf16* __restrict__ q,
                        const float* __restrict__ g, const float* __restrict__ b)
{
  int row  = blockIdx.x*4 + (threadIdx.x >> 6);
  int lane = threadIdx.x & 63;
  long o = (long)row*512 + lane*8;
  BV Q;
  Q.u = *(const uint4*)(q + o);
  float s[8]; float sum=0.f, sq=0.f;
  #pragma unroll
  for (int j=0;j<8;++j){ s[j] = b2f(Q.h[j]); sum += s[j]; sq += s[j]*s[j]; }
  sum = wsum(sum); sq = wsum(sq);
  float mean = sum * 0.001953125f;
  float var  = sq  * 0.001953125f - mean*mean;
  float rstd = rsqrtf(var + 1e-5f);
  const float4* g4 = (const float4*)(g + lane*8);
  const float4* b4 = (const float4*)(b + lane*8);
  float4 g0=g4[0], g1=g4[1], b0=b4[0], b1=b4[1];
  float gg[8] = {g0.x,g0.y,g0.z,g0.w,g1.x,g1.y,g1.z,g1.w};
  float bb[8] = {b0.x,b0.y,b0.z,b0.w,b1.x,b1.y,b1.z,b1.w};
  BV O;
  #pragma unroll
  for (int j=0;j<8;++j) O.h[j] = f2b((s[j]-mean)*rstd*gg[j] + bb[j]);
  *(uint4*)(q + o) = O.u;
}

// cross-attention, K/V length = 4. wave per (b,q)-row. qMod>0: Q rows shared mod qMod.
// (kept for layer 0, where the 96 shared q rows broadcast across b)
__global__ void attn_k(const bf16* __restrict__ qsrc, int qMod,
                       const bf16* __restrict__ kvh, bf16* __restrict__ dst)
{
  int row  = blockIdx.x*4 + (threadIdx.x >> 6);
  int lane = threadIdx.x & 63;
  int b = row / 96;
  int qRow = qMod ? (row % qMod) : row;
  int d = (lane >> 3)*64 + (lane & 7)*8;
  BV Q;
  Q.u = *(const uint4*)(qsrc + (long)qRow*512 + d);
  float qf[8];
  #pragma unroll
  for (int j=0;j<8;++j) qf[j] = b2f(Q.h[j]);
  float s[4];
  #pragma unroll
  for (int c=0;c<4;++c){
    BV K; K.u = *(const uint4*)(kvh + (long)(b*4+c)*1024 + d);
    float p = 0.f;
    #pragma unroll
    for (int j=0;j<8;++j) p += qf[j]*b2f(K.h[j]);
    p += __shfl_xor(p,1); p += __shfl_xor(p,2); p += __shfl_xor(p,4);
    s[c] = p * 0.125f;
  }
  float mx = fmaxf(fmaxf(s[0],s[1]), fmaxf(s[2],s[3]));
  float e0=expf(s[0]-mx), e1=expf(s[1]-mx), e2=expf(s[2]-mx), e3=expf(s[3]-mx);
  float inv = 1.f/(e0+e1+e2+e3);
  float p4[4] = {e0*inv, e1*inv, e2*inv, e3*inv};
  float o[8] = {0,0,0,0,0,0,0,0};
  #pragma unroll
  for (int c=0;c<4;++c){
    BV V; V.u = *(const uint4*)(kvh + (long)(b*4+c)*1024 + 512 + d);
    #pragma unroll
    for (int j=0;j<8;++j) o[j] += p4[c]*b2f(V.h[j]);
  }
  BV O;
  #pragma unroll
  for (int j=0;j<8;++j) O.h[j] = f2b(o[j]);
  *(uint4*)(dst + (long)row*512 + d) = O.u;
}

// heads tail: pred3 / conf / dp3 + occlusion select.  wave per row.
__global__ void finalize_k(const bf16* __restrict__ feat, const bf16* __restrict__ p2dp2,
                           const float* __restrict__ cw, const float* __restrict__ cb,
                           const float* __restrict__ pw3, const float* __restrict__ pb3,
                           const float* __restrict__ dw3, const float* __restrict__ db3,
                           const int* __restrict__ occ, const float* __restrict__ okp,
                           float* __restrict__ out)
{
  int row  = blockIdx.x*4 + (threadIdx.x >> 6);
  int lane = threadIdx.x & 63;
  BV F; F.u = *(const uint4*)(feat + (long)row*512 + lane*8);
  const float4* c4 = (const float4*)(cw + lane*8);
  float4 ca = c4[0], cbv = c4[1];
  float cwv[8] = {ca.x,ca.y,ca.z,ca.w,cbv.x,cbv.y,cbv.z,cbv.w};
  float pc = 0.f;
  #pragma unroll
  for (int j=0;j<8;++j) pc += b2f(F.h[j]) * cwv[j];
  float sc = wsum(pc);
  int k = lane*2;
  long o2 = (long)row*256;
  float a0 = b2f(p2dp2[o2 + k]),       a1 = b2f(p2dp2[o2 + k + 1]);
  float d0 = b2f(p2dp2[o2 + 128 + k]), d1 = b2f(p2dp2[o2 + 128 + k + 1]);
  float sx = a0*pw3[k*2]   + a1*pw3[(k+1)*2];
  float sy = a0*pw3[k*2+1] + a1*pw3[(k+1)*2+1];
  float sd = d0*dw3[k]     + d1*dw3[k+1];
  sx = wsum(sx); sy = wsum(sy); sd = wsum(sd);
  if (lane == 0) {
    bool occl = (occ[row] == 0);
    out[row*2]   = occl ? (sx + pb3[0]) : okp[row*2];
    out[row*2+1] = occl ? (sy + pb3[1]) : okp[row*2+1];
    out[98304 + row] = occl ? 1.f/(1.f + expf(-(sc + cb[0]))) : 0.f;
    float dd = sd + db3[0];
    float sp = fmaxf(dd, 0.f) + log1pf(expf(-fabsf(dd)));   // softplus
    out[147456 + row] = occl ? sp : 0.f;
  }
}

extern "C" void kernel_launch(void* const* d_in, const int* in_sizes, int n_in,
                              void* d_out, int out_size, void* d_ws, size_t ws_size,
                              hipStream_t stream)
{
  const float* enc  = (const float*)d_in[0];
  const float* okp  = (const float*)d_in[1];
  const int*   occ  = (const int*)  d_in[3];
  const float* kp   = (const float*)d_in[4];
  const float* vw   = (const float*)d_in[5];
  const float* Wq   = (const float*)d_in[6];
  const float* bq   = (const float*)d_in[7];
  const float* Wk   = (const float*)d_in[8];
  const float* bk   = (const float*)d_in[9];
  const float* Wv   = (const float*)d_in[10];
  const float* bv   = (const float*)d_in[11];
  const float* Wo   = (const float*)d_in[12];
  const float* bo   = (const float*)d_in[13];
  const float* ln1g = (const float*)d_in[14];
  const float* ln1b = (const float*)d_in[15];
  const float* ln2g = (const float*)d_in[16];
  const float* ln2b = (const float*)d_in[17];
  const float* fw1  = (const float*)d_in[18];
  const float* fb1  = (const float*)d_in[19];
  const float* fw2  = (const float*)d_in[20];
  const float* fb2  = (const float*)d_in[21];
  const float* pw1  = (const float*)d_in[22];
  const float* pb1  = (const float*)d_in[23];
  const float* pw2  = (const float*)d_in[24];
  const float* pb2  = (const float*)d_in[25];
  const float* pw3  = (const float*)d_in[26];
  const float* pb3  = (const float*)d_in[27];
  // 28..33: de_w1/de_b1/de_w2/de_b2/mp_w/mp_b -> dead w.r.t. outputs, skipped
  const float* dw1  = (const float*)d_in[34];
  const float* db1  = (const float*)d_in[35];
  const float* dw2  = (const float*)d_in[36];
  const float* db2  = (const float*)d_in[37];
  const float* dw3  = (const float*)d_in[38];
  const float* db3  = (const float*)d_in[39];
  const float* cw   = (const float*)d_in[40];
  const float* cb   = (const float*)d_in[41];

  uint8_t* base = (uint8_t*)d_ws;
  size_t off = 0;
  auto alloc = [&](size_t bytes) -> void* {
    void* p = base + off;
    off = (off + bytes + 255) & ~(size_t)255;
    return p;
  };
  // weights (bf16, K-contiguous)
  bf16*  wqT  = (bf16*) alloc(4ull*512*512*2);
  bf16*  kvT  = (bf16*) alloc(4ull*1024*512*2);
  bf16*  woT  = (bf16*) alloc(4ull*512*512*2);
  bf16*  w1T  = (bf16*) alloc(4ull*2048*512*2);
  bf16*  w2T  = (bf16*) alloc(4ull*512*2048*2);
  bf16*  pd1T = (bf16*) alloc(512ull*512*2);
  bf16*  pw2T = (bf16*) alloc(128ull*256*2);
  bf16*  dw2T = (bf16*) alloc(128ull*256*2);
  float* bkvb = (float*)alloc(4ull*1024*4);
  float* pd1b = (float*)alloc(512ull*4);
  // activations
  bf16*  mem16= (bf16*) alloc(2048ull*512*2);
  bf16*  kv16 = (bf16*) alloc(2048ull*1024*2);
  bf16*  q96  = (bf16*) alloc(128ull*512*2);
  bf16*  qh96 = (bf16*) alloc(128ull*512*2);
  bf16*  q16  = (bf16*) alloc(49152ull*512*2);    // 48 MiB
  bf16*  bufQH= (bf16*) alloc(49152ull*512*2);    // 48 MiB
  // bounce buffer: largest tier that fits (49152 = unchunked FFN, fewest dispatch tails)
  size_t remainB = (ws_size > off) ? (ws_size - off) : 0;
  int chunkRows;
  if      (remainB >= 49152ull*2048*2 + 512) chunkRows = 49152;
  else if (remainB >= 24576ull*2048*2 + 512) chunkRows = 24576;
  else if (remainB >= 16384ull*2048*2 + 512) chunkRows = 16384;
  else if (remainB >= 12288ull*2048*2 + 512) chunkRows = 12288;
  else                                        chunkRows = 6144;
  bf16*  bufF1= (bf16*) alloc((size_t)chunkRows*2048*2);
  if (off > ws_size) return;
  const int nCh = 49152 / chunkRows;

  dim3 T(256);
  // ---- prep ----
  transpose_w<<<dim3(16,16,4), T, 0, stream>>>(Wq,  wqT, 512, 512*512, 512*512, 0, 512);
  transpose_w<<<dim3(16,16,4), T, 0, stream>>>(Wk,  kvT, 512, 512*512, 1024*512, 0, 512);
  transpose_w<<<dim3(16,16,4), T, 0, stream>>>(Wv,  kvT, 512, 512*512, 1024*512, 512, 512);
  transpose_w<<<dim3(16,16,4), T, 0, stream>>>(Wo,  woT, 512, 512*512, 512*512, 0, 512);
  transpose_w<<<dim3(64,16,4), T, 0, stream>>>(fw1, w1T, 2048, 512*2048, 2048*512, 0, 512);
  transpose_w<<<dim3(16,64,4), T, 0, stream>>>(fw2, w2T, 512, 2048*512, 512*2048, 0, 2048);
  transpose_w<<<dim3(8,16,1),  T, 0, stream>>>(pw1, pd1T, 256, 0, 0, 0,   512);
  transpose_w<<<dim3(8,16,1),  T, 0, stream>>>(dw1, pd1T, 256, 0, 0, 256, 512);
  transpose_w<<<dim3(4,8,1),   T, 0, stream>>>(pw2, pw2T, 128, 0, 0, 0, 256);
  transpose_w<<<dim3(4,8,1),   T, 0, stream>>>(dw2, dw2T, 128, 0, 0, 0, 256);
  concat2<<<dim3(4,4), T, 0, stream>>>(bkvb, 1024, bk, 512, 512, bv, 512, 512);
  concat2<<<dim3(2,1), T, 0, stream>>>(pd1b, 512, pb1, 256, 256, db1, 256, 256);
  f32_to_bf16_k<<<dim3(1024), T, 0, stream>>>(enc, mem16, 2048ll*512);
  init_q<<<dim3(12288), T, 0, stream>>>(vw, kp, q16);
  init_q96<<<dim3(24), T, 0, stream>>>(vw, kp, q96);

  // ---- 4 cross-attention layers ----
  for (int l = 0; l < 4; ++l) {
    // K/V projection FIRST (fused-attn epilogue of the Wq GEMM reads kv16)
    gemm_bt<0><<<dim3(8,16),  T, 0, stream>>>(mem16, 512, kvT + l*524288, bkvb + l*1024,
                                              kv16, 1024, 512, nullptr);
    if (l == 0) {
      // layer 0: 96 distinct q rows -> tiny Q-projection + broadcast attention
      gemm_bt<0><<<dim3(4,1), T, 0, stream>>>(q96, 512, wqT, bq, qh96, 512, 512, nullptr);
      attn_k<<<dim3(12288), T, 0, stream>>>(qh96, 96, kv16, bufQH);
    } else {
      // layers 1-3: Wq GEMM with FUSED attention epilogue -> bufQH = attn output
      gemm_bt<3><<<dim3(4,384), T, 0, stream>>>(q16, 512, wqT + l*262144, bq + l*512,
                                                bufQH, 512, 512, kv16);
    }
    // Wo with fused residual: q16 <- q16 + attn@Wo + bo  (in place, tile-local)
    gemm_bt<2><<<dim3(4,384), T, 0, stream>>>(bufQH, 512, woT + l*262144, bo + l*512,
                                              q16, 512, 512, q16);
    ln_only<<<dim3(12288), T, 0, stream>>>(q16, ln1g + l*512, ln1b + l*512);
    for (int c = 0; c < nCh; ++c) {   // FFN chunks (1 chunk if workspace allows)
      bf16* qc = q16 + (long)c*chunkRows*512;
      gemm_bt<1><<<dim3(16, chunkRows>>7), T, 0, stream>>>(qc, 512,
                                                w1T + l*1048576, fb1 + l*2048, bufF1, 2048, 512, nullptr);
      gemm_bt<2><<<dim3(4, chunkRows>>7),  T, 0, stream>>>(bufF1, 2048,
                                                w2T + l*1048576, fb2 + l*512,
                                                qc, 512, 2048, qc);
      ln_only<<<dim3(chunkRows>>2), T, 0, stream>>>(qc, ln2g + l*512, ln2b + l*512);
    }
  }

  // ---- heads ----
  gemm_bt<1><<<dim3(4,384), T, 0, stream>>>(q16, 512, pd1T, pd1b, bufQH, 512, 512, nullptr);
  gemm_bt<1><<<dim3(1,384), T, 0, stream>>>(bufQH, 512, pw2T, pb2, bufF1, 256, 256, nullptr);
  gemm_bt<1><<<dim3(1,384), T, 0, stream>>>(bufQH + 256, 512, dw2T, db2, bufF1 + 128, 256, 256, nullptr);
  finalize_k<<<dim3(12288), T, 0, stream>>>(q16, bufF1, cw, cb, pw3, pb3, dw3, db3,
                                            occ, okp, (float*)d_out);
}

// Round 20
// 1603.269 us; speedup vs baseline: 1.0013x; 1.0013x over previous
//
#include <hip/hip_runtime.h>
#include <hip/hip_bf16.h>
#include <stdint.h>

using bf16 = __hip_bfloat16;
typedef __attribute__((ext_vector_type(8))) short short8;
typedef __attribute__((ext_vector_type(4))) float f32x4;

#define GLD16(gptr, lptr) \
  __builtin_amdgcn_global_load_lds((const __attribute__((address_space(1))) void*)(gptr), \
                                   (__attribute__((address_space(3))) void*)(lptr), 16, 0, 0)

__device__ __forceinline__ float b2f(bf16 h){ return __bfloat162float(h); }
__device__ __forceinline__ bf16  f2b(float f){ return __float2bfloat16(f); }
// tanh-approx GELU in exp form (identical math, 1 hw transcendental):
__device__ __forceinline__ float geluf(float x){
  float t2 = 1.5957691216057308f * (x + 0.044715f*x*x*x);
  return x / (1.0f + __expf(-t2));
}
__device__ __forceinline__ float wsum(float v){
  v += __shfl_xor(v,32); v += __shfl_xor(v,16); v += __shfl_xor(v,8);
  v += __shfl_xor(v,4);  v += __shfl_xor(v,2);  v += __shfl_xor(v,1);
  return v;
}

union BV { uint4 u; bf16 h[8]; };

// ---------------- bf16 MFMA GEMM:  C[M][N] = A[M][K] @ Bt[N][K]^T + bias ----------------
// FINAL converged config (1604-1607 us across 4 runs): 128x128 tile, BK=64, 4 waves,
// single-buffer LDS 34816 B -> 4 blocks/CU, drain-per-step sync (proven sound),
// T2 XOR-swizzle via pre-swizzled global source (rule #21).
// EPI: 0 = bias, 1 = bias+gelu, 2 = bias + residual add (in-place, tile-local),
//      3 = bias + FUSED CROSS-ATTENTION (tile covers exactly 2 heads; thread ->
//          (row, local head): 4 scores from LDS row-segment, softmax, V-accumulate
//          from L2-resident kv (Res = kv base), direct write; no new sync).
template<int EPI>
__global__ __launch_bounds__(256, 4)
void gemm_bt(const bf16* __restrict__ A, int lda,
             const bf16* __restrict__ Bt,
             const float* __restrict__ bias,
             bf16* __restrict__ C, int ldc, int K,
             const bf16* __restrict__ Res)
{
  // K-loop: [A 128x64 | B 128x64] = 32 KB; epilogue reuses as [128][136] = 34816 B
  __shared__ __align__(16) bf16 smem[17408];
  const int tid  = threadIdx.x;
  const int wave = tid >> 6;
  const int lane = tid & 63;

  const int nwg = gridDim.x * gridDim.y;
  int bid = blockIdx.x + gridDim.x * blockIdx.y;
  if ((nwg & 7) == 0) bid = (bid & 7) * (nwg >> 3) + (bid >> 3);
  const int bx = bid % gridDim.x;
  const int by = bid / gridDim.x;
  const long mBlk = (long)by * 128;
  const int  nBlk = bx * 128;
  const int wm = (wave >> 1) * 64;
  const int wn = (wave & 1)  * 64;

  // staging source (pre-swizzled): lane l fetches k-chunk j=(l&7)^(l>>3) of its row
  const int lr = lane >> 3;              // 0..7
  const int kc = ((lane & 7) ^ lr) << 3;
  const bf16* aS = A  + (mBlk + wave*32 + lr) * (long)lda + kc;
  const bf16* bS = Bt + (long)(nBlk + wave*32 + lr) * K   + kc;

  // fragment read geometry
  const int sA = lane >> 4;              // 0..3
  const int rA = wm + (lane & 15);
  const int rB = wn + (lane & 15);
  const int xA = rA & 7, xB = rB & 7;

  f32x4 acc[4][4];
  #pragma unroll
  for (int m=0;m<4;++m)
    #pragma unroll
    for (int n=0;n<4;++n)
      acc[m][n] = (f32x4){0.f,0.f,0.f,0.f};

  const int nt = K >> 6;
  for (int t = 0; t < nt; ++t) {
    {
      bf16* sAl = smem + wave*2048;
      bf16* sBl = smem + 8192 + wave*2048;
      const int ko = t*64;
      #pragma unroll
      for (int c=0;c<4;++c) {
        GLD16(aS + (long)c*8*lda + ko, sAl + c*512);
        GLD16(bS + (long)c*8*K   + ko, sBl + c*512);
      }
    }
    __syncthreads();   // drains vmcnt+lgkmcnt: tile landed, all waves ready
    #pragma unroll
    for (int ks=0; ks<2; ++ks) {
      const int j = (ks<<2) + sA;
      short8 af[4], bfv[4];
      #pragma unroll
      for (int m=0;m<4;++m)
        af[m]  = *(const short8*)&smem[(rA + m*16)*64 + ((j ^ xA) << 3)];
      #pragma unroll
      for (int n=0;n<4;++n)
        bfv[n] = *(const short8*)&smem[8192 + (rB + n*16)*64 + ((j ^ xB) << 3)];
      #pragma unroll
      for (int m=0;m<4;++m)
        #pragma unroll
        for (int n=0;n<4;++n)
          acc[m][n] = __builtin_amdgcn_mfma_f32_16x16x32_bf16(af[m], bfv[n], acc[m][n], 0, 0, 0);
    }
    __syncthreads();   // all reads done before next STAGE / epilogue overwrites
  }

  // ---- epilogue: bias(+gelu) -> LDS stage (padded rows) ----
  #pragma unroll
  for (int n=0;n<4;++n) {
    const int col = wn + n*16 + (lane & 15);
    float bi = bias[nBlk + col];
    #pragma unroll
    for (int m=0;m<4;++m) {
      #pragma unroll
      for (int j=0;j<4;++j) {
        float x = acc[m][n][j] + bi;
        if (EPI == 1) x = geluf(x);
        smem[(wm + m*16 + (lane>>4)*4 + j)*136 + col] = f2b(x);
      }
    }
  }
  __syncthreads();

  if (EPI == 3) {
    // ---- fused cross-attention (KV len 4): thread -> (row, local head) ----
    const int row = tid >> 1;            // 0..127
    const int lh  = tid & 1;             // local head within this tile's 2 heads
    const long grow = mBlk + row;
    const int b = (int)(grow / 96);
    const bf16* qrow = &smem[row*136 + lh*64];             // this (row,head)'s qh segment
    const bf16* kvb  = Res + (long)b*4096 + nBlk + lh*64;  // K base; +c*1024; V at +512
    float s[4];
    #pragma unroll
    for (int c=0;c<4;++c){
      const bf16* kcp = kvb + c*1024;
      float p = 0.f;
      #pragma unroll
      for (int k0=0;k0<64;k0+=8){
        BV q8, k8;
        q8.u = *(const uint4*)(qrow + k0);
        k8.u = *(const uint4*)(kcp + k0);
        #pragma unroll
        for (int j=0;j<8;++j) p += b2f(q8.h[j]) * b2f(k8.h[j]);
      }
      s[c] = p * 0.125f;
    }
    float mx = fmaxf(fmaxf(s[0],s[1]), fmaxf(s[2],s[3]));
    float e0=__expf(s[0]-mx), e1=__expf(s[1]-mx), e2=__expf(s[2]-mx), e3=__expf(s[3]-mx);
    float inv = 1.f/(e0+e1+e2+e3);
    float p4[4] = {e0*inv, e1*inv, e2*inv, e3*inv};
    #pragma unroll
    for (int k0=0;k0<64;k0+=8){
      float o8[8] = {0,0,0,0,0,0,0,0};
      #pragma unroll
      for (int c=0;c<4;++c){
        BV v8; v8.u = *(const uint4*)(kvb + c*1024 + 512 + k0);
        #pragma unroll
        for (int j=0;j<8;++j) o8[j] += p4[c]*b2f(v8.h[j]);
      }
      BV O;
      #pragma unroll
      for (int j=0;j<8;++j) O.h[j] = f2b(o8[j]);
      *(uint4*)&C[grow*(long)ldc + nBlk + lh*64 + k0] = O.u;
    }
  } else {
    // ---- coalesced uint4 stores (EPI 0/1/2) ----
    #pragma unroll
    for (int it=0; it<8; ++it) {
      int o = it*2048 + tid*8;
      int row = o >> 7, col = o & 127;
      uint4 v = *(const uint4*)&smem[row*136 + col];
      if (EPI == 2) {   // fused residual add
        uint4 r = *(const uint4*)&Res[(mBlk + row)*(long)ldc + nBlk + col];
        BV a, b, oo;
        a.u = v; b.u = r;
        #pragma unroll
        for (int j=0;j<8;++j) oo.h[j] = f2b(b2f(a.h[j]) + b2f(b.h[j]));
        v = oo.u;
      }
      *(uint4*)&C[(mBlk + row)*(long)ldc + nBlk + col] = v;
    }
  }
}

// ---------------- prep: fp32 W[K][N] -> bf16 Wt[N][K] (tiled transpose) ----------------
__global__ void transpose_w(const float* __restrict__ src, bf16* __restrict__ dst,
                            int N, long srcStride, long dstStride, int dstRowOff, int dstLd)
{
  __shared__ float t[32][33];
  src += (long)blockIdx.z * srcStride;
  dst += (long)blockIdx.z * dstStride;
  int n0 = blockIdx.x*32, k0 = blockIdx.y*32;
  int tx = threadIdx.x & 31, ty = threadIdx.x >> 5;
  #pragma unroll
  for (int r=0;r<4;++r) t[ty + r*8][tx] = src[(long)(k0+ty+r*8)*N + n0+tx];
  __syncthreads();
  #pragma unroll
  for (int r=0;r<4;++r)
    dst[(long)(dstRowOff + n0 + ty + r*8)*dstLd + k0 + tx] = f2b(t[tx][ty+r*8]);
}

__global__ void f32_to_bf16_k(const float* __restrict__ src, bf16* __restrict__ dst, long n)
{
  long i = ((long)blockIdx.x*256 + threadIdx.x) * 4;
  if (i + 3 < n) {
    float4 v = *(const float4*)(src + i);
    dst[i+0]=f2b(v.x); dst[i+1]=f2b(v.y); dst[i+2]=f2b(v.z); dst[i+3]=f2b(v.w);
  }
}

__global__ void concat2(float* __restrict__ dst, long dStride,
                        const float* __restrict__ a, long aStride, int na,
                        const float* __restrict__ b, long bStride, int nb)
{
  int z = blockIdx.y;
  int i = blockIdx.x*256 + threadIdx.x;
  if (i < na) dst[z*dStride + i] = a[z*aStride + i];
  else if (i < na + nb) dst[z*dStride + i] = b[z*bStride + (i - na)];
}

// q0[b][c*24+n][d] = view_emb[c][d] + kp_emb[n][d]
__global__ void init_q(const float* __restrict__ vw, const float* __restrict__ kp,
                       bf16* __restrict__ q)
{
  long gid = (long)blockIdx.x*256 + threadIdx.x;  // 512*96*64 total
  int b  = (int)(gid / 6144);
  int r  = (int)(gid % 6144);
  int cn = r >> 6;
  int d0 = (r & 63) * 8;
  int c = cn / 24, n = cn % 24;
  const float4* v4 = (const float4*)(vw + c*512 + d0);
  const float4* k4 = (const float4*)(kp + n*512 + d0);
  float4 va = v4[0], vb = v4[1], ka = k4[0], kb = k4[1];
  BV o;
  o.h[0]=f2b(va.x+ka.x); o.h[1]=f2b(va.y+ka.y); o.h[2]=f2b(va.z+ka.z); o.h[3]=f2b(va.w+ka.w);
  o.h[4]=f2b(vb.x+kb.x); o.h[5]=f2b(vb.y+kb.y); o.h[6]=f2b(vb.z+kb.z); o.h[7]=f2b(vb.w+kb.w);
  *(uint4*)(q + (long)b*49152 + cn*512 + d0) = o.u;
}

// q96[cn][d] = view_emb[c][d] + kp_emb[n][d]  (the 96 distinct pre-layer-1 rows)
__global__ void init_q96(const float* __restrict__ vw, const float* __restrict__ kp,
                         bf16* __restrict__ q96)
{
  int gid = blockIdx.x*256 + threadIdx.x;   // 96*64 = 6144 threads
  int cn = gid >> 6;
  int d0 = (gid & 63) * 8;
  int c = cn / 24, n = cn % 24;
  const float4* v4 = (const float4*)(vw + c*512 + d0);
  const float4* k4 = (const float4*)(kp + n*512 + d0);
  float4 va = v4[0], vb = v4[1], ka = k4[0], kb = k4[1];
  BV o;
  o.h[0]=f2b(va.x+ka.x); o.h[1]=f2b(va.y+ka.y); o.h[2]=f2b(va.z+ka.z); o.h[3]=f2b(va.w+ka.w);
  o.h[4]=f2b(vb.x+kb.x); o.h[5]=f2b(vb.y+kb.y); o.h[6]=f2b(vb.z+kb.z); o.h[7]=f2b(vb.w+kb.w);
  *(uint4*)(q96 + (long)cn*512 + d0) = o.u;
}

// q = LN(q) * g + b  in place  (wave per row of 512; residual already folded by gemm EPI=2)
__global__ void ln_only(bf16* __restrict__ q,
                        const float* __restrict__ g, const float* __restrict__ b)
{
  int row  = blockIdx.x*4 + (threadIdx.x >> 6);
  int lane = threadIdx.x & 63;
  long o = (long)row*512 + lane*8;
  BV Q;
  Q.u = *(const uint4*)(q + o);
  float s[8]; float sum=0.f, sq=0.f;
  #pragma unroll
  for (int j=0;j<8;++j){ s[j] = b2f(Q.h[j]); sum += s[j]; sq += s[j]*s[j]; }
  sum = wsum(sum); sq = wsum(sq);
  float mean = sum * 0.001953125f;
  float var  = sq  * 0.001953125f - mean*mean;
  float rstd = rsqrtf(var + 1e-5f);
  const float4* g4 = (const float4*)(g + lane*8);
  const float4* b4 = (const float4*)(b + lane*8);
  float4 g0=g4[0], g1=g4[1], b0=b4[0], b1=b4[1];
  float gg[8] = {g0.x,g0.y,g0.z,g0.w,g1.x,g1.y,g1.z,g1.w};
  float bb[8] = {b0.x,b0.y,b0.z,b0.w,b1.x,b1.y,b1.z,b1.w};
  BV O;
  #pragma unroll
  for (int j=0;j<8;++j) O.h[j] = f2b((s[j]-mean)*rstd*gg[j] + bb[j]);
  *(uint4*)(q + o) = O.u;
}

// cross-attention, K/V length = 4. wave per (b,q)-row. qMod>0: Q rows shared mod qMod.
// (kept for layer 0, where the 96 shared q rows broadcast across b)
__global__ void attn_k(const bf16* __restrict__ qsrc, int qMod,
                       const bf16* __restrict__ kvh, bf16* __restrict__ dst)
{
  int row  = blockIdx.x*4 + (threadIdx.x >> 6);
  int lane = threadIdx.x & 63;
  int b = row / 96;
  int qRow = qMod ? (row % qMod) : row;
  int d = (lane >> 3)*64 + (lane & 7)*8;
  BV Q;
  Q.u = *(const uint4*)(qsrc + (long)qRow*512 + d);
  float qf[8];
  #pragma unroll
  for (int j=0;j<8;++j) qf[j] = b2f(Q.h[j]);
  float s[4];
  #pragma unroll
  for (int c=0;c<4;++c){
    BV K; K.u = *(const uint4*)(kvh + (long)(b*4+c)*1024 + d);
    float p = 0.f;
    #pragma unroll
    for (int j=0;j<8;++j) p += qf[j]*b2f(K.h[j]);
    p += __shfl_xor(p,1); p += __shfl_xor(p,2); p += __shfl_xor(p,4);
    s[c] = p * 0.125f;
  }
  float mx = fmaxf(fmaxf(s[0],s[1]), fmaxf(s[2],s[3]));
  float e0=expf(s[0]-mx), e1=expf(s[1]-mx), e2=expf(s[2]-mx), e3=expf(s[3]-mx);
  float inv = 1.f/(e0+e1+e2+e3);
  float p4[4] = {e0*inv, e1*inv, e2*inv, e3*inv};
  float o[8] = {0,0,0,0,0,0,0,0};
  #pragma unroll
  for (int c=0;c<4;++c){
    BV V; V.u = *(const uint4*)(kvh + (long)(b*4+c)*1024 + 512 + d);
    #pragma unroll
    for (int j=0;j<8;++j) o[j] += p4[c]*b2f(V.h[j]);
  }
  BV O;
  #pragma unroll
  for (int j=0;j<8;++j) O.h[j] = f2b(o[j]);
  *(uint4*)(dst + (long)row*512 + d) = O.u;
}

// heads tail: pred3 / conf / dp3 + occlusion select.  wave per row.
__global__ void finalize_k(const bf16* __restrict__ feat, const bf16* __restrict__ p2dp2,
                           const float* __restrict__ cw, const float* __restrict__ cb,
                           const float* __restrict__ pw3, const float* __restrict__ pb3,
                           const float* __restrict__ dw3, const float* __restrict__ db3,
                           const int* __restrict__ occ, const float* __restrict__ okp,
                           float* __restrict__ out)
{
  int row  = blockIdx.x*4 + (threadIdx.x >> 6);
  int lane = threadIdx.x & 63;
  BV F; F.u = *(const uint4*)(feat + (long)row*512 + lane*8);
  const float4* c4 = (const float4*)(cw + lane*8);
  float4 ca = c4[0], cbv = c4[1];
  float cwv[8] = {ca.x,ca.y,ca.z,ca.w,cbv.x,cbv.y,cbv.z,cbv.w};
  float pc = 0.f;
  #pragma unroll
  for (int j=0;j<8;++j) pc += b2f(F.h[j]) * cwv[j];
  float sc = wsum(pc);
  int k = lane*2;
  long o2 = (long)row*256;
  float a0 = b2f(p2dp2[o2 + k]),       a1 = b2f(p2dp2[o2 + k + 1]);
  float d0 = b2f(p2dp2[o2 + 128 + k]), d1 = b2f(p2dp2[o2 + 128 + k + 1]);
  float sx = a0*pw3[k*2]   + a1*pw3[(k+1)*2];
  float sy = a0*pw3[k*2+1] + a1*pw3[(k+1)*2+1];
  float sd = d0*dw3[k]     + d1*dw3[k+1];
  sx = wsum(sx); sy = wsum(sy); sd = wsum(sd);
  if (lane == 0) {
    bool occl = (occ[row] == 0);
    out[row*2]   = occl ? (sx + pb3[0]) : okp[row*2];
    out[row*2+1] = occl ? (sy + pb3[1]) : okp[row*2+1];
    out[98304 + row] = occl ? 1.f/(1.f + expf(-(sc + cb[0]))) : 0.f;
    float dd = sd + db3[0];
    float sp = fmaxf(dd, 0.f) + log1pf(expf(-fabsf(dd)));   // softplus
    out[147456 + row] = occl ? sp : 0.f;
  }
}

extern "C" void kernel_launch(void* const* d_in, const int* in_sizes, int n_in,
                              void* d_out, int out_size, void* d_ws, size_t ws_size,
                              hipStream_t stream)
{
  const float* enc  = (const float*)d_in[0];
  const float* okp  = (const float*)d_in[1];
  const int*   occ  = (const int*)  d_in[3];
  const float* kp   = (const float*)d_in[4];
  const float* vw   = (const float*)d_in[5];
  const float* Wq   = (const float*)d_in[6];
  const float* bq   = (const float*)d_in[7];
  const float* Wk   = (const float*)d_in[8];
  const float* bk   = (const float*)d_in[9];
  const float* Wv   = (const float*)d_in[10];
  const float* bv   = (const float*)d_in[11];
  const float* Wo   = (const float*)d_in[12];
  const float* bo   = (const float*)d_in[13];
  const float* ln1g = (const float*)d_in[14];
  const float* ln1b = (const float*)d_in[15];
  const float* ln2g = (const float*)d_in[16];
  const float* ln2b = (const float*)d_in[17];
  const float* fw1  = (const float*)d_in[18];
  const float* fb1  = (const float*)d_in[19];
  const float* fw2  = (const float*)d_in[20];
  const float* fb2  = (const float*)d_in[21];
  const float* pw1  = (const float*)d_in[22];
  const float* pb1  = (const float*)d_in[23];
  const float* pw2  = (const float*)d_in[24];
  const float* pb2  = (const float*)d_in[25];
  const float* pw3  = (const float*)d_in[26];
  const float* pb3  = (const float*)d_in[27];
  // 28..33: de_w1/de_b1/de_w2/de_b2/mp_w/mp_b -> dead w.r.t. outputs, skipped
  const float* dw1  = (const float*)d_in[34];
  const float* db1  = (const float*)d_in[35];
  const float* dw2  = (const float*)d_in[36];
  const float* db2  = (const float*)d_in[37];
  const float* dw3  = (const float*)d_in[38];
  const float* db3  = (const float*)d_in[39];
  const float* cw   = (const float*)d_in[40];
  const float* cb   = (const float*)d_in[41];

  uint8_t* base = (uint8_t*)d_ws;
  size_t off = 0;
  auto alloc = [&](size_t bytes) -> void* {
    void* p = base + off;
    off = (off + bytes + 255) & ~(size_t)255;
    return p;
  };
  // weights (bf16, K-contiguous)
  bf16*  wqT  = (bf16*) alloc(4ull*512*512*2);
  bf16*  kvT  = (bf16*) alloc(4ull*1024*512*2);
  bf16*  woT  = (bf16*) alloc(4ull*512*512*2);
  bf16*  w1T  = (bf16*) alloc(4ull*2048*512*2);
  bf16*  w2T  = (bf16*) alloc(4ull*512*2048*2);
  bf16*  pd1T = (bf16*) alloc(512ull*512*2);
  bf16*  pw2T = (bf16*) alloc(128ull*256*2);
  bf16*  dw2T = (bf16*) alloc(128ull*256*2);
  float* bkvb = (float*)alloc(4ull*1024*4);
  float* pd1b = (float*)alloc(512ull*4);
  // activations
  bf16*  mem16= (bf16*) alloc(2048ull*512*2);
  bf16*  kv16 = (bf16*) alloc(2048ull*1024*2);
  bf16*  q96  = (bf16*) alloc(128ull*512*2);
  bf16*  qh96 = (bf16*) alloc(128ull*512*2);
  bf16*  q16  = (bf16*) alloc(49152ull*512*2);    // 48 MiB
  bf16*  bufQH= (bf16*) alloc(49152ull*512*2);    // 48 MiB
  // bounce buffer: largest tier that fits (49152 = unchunked FFN, fewest dispatch tails)
  size_t remainB = (ws_size > off) ? (ws_size - off) : 0;
  int chunkRows;
  if      (remainB >= 49152ull*2048*2 + 512) chunkRows = 49152;
  else if (remainB >= 24576ull*2048*2 + 512) chunkRows = 24576;
  else if (remainB >= 16384ull*2048*2 + 512) chunkRows = 16384;
  else if (remainB >= 12288ull*2048*2 + 512) chunkRows = 12288;
  else                                        chunkRows = 6144;
  bf16*  bufF1= (bf16*) alloc((size_t)chunkRows*2048*2);
  if (off > ws_size) return;
  const int nCh = 49152 / chunkRows;

  dim3 T(256);
  // ---- prep ----
  transpose_w<<<dim3(16,16,4), T, 0, stream>>>(Wq,  wqT, 512, 512*512, 512*512, 0, 512);
  transpose_w<<<dim3(16,16,4), T, 0, stream>>>(Wk,  kvT, 512, 512*512, 1024*512, 0, 512);
  transpose_w<<<dim3(16,16,4), T, 0, stream>>>(Wv,  kvT, 512, 512*512, 1024*512, 512, 512);
  transpose_w<<<dim3(16,16,4), T, 0, stream>>>(Wo,  woT, 512, 512*512, 512*512, 0, 512);
  transpose_w<<<dim3(64,16,4), T, 0, stream>>>(fw1, w1T, 2048, 512*2048, 2048*512, 0, 512);
  transpose_w<<<dim3(16,64,4), T, 0, stream>>>(fw2, w2T, 512, 2048*512, 512*2048, 0, 2048);
  transpose_w<<<dim3(8,16,1),  T, 0, stream>>>(pw1, pd1T, 256, 0, 0, 0,   512);
  transpose_w<<<dim3(8,16,1),  T, 0, stream>>>(dw1, pd1T, 256, 0, 0, 256, 512);
  transpose_w<<<dim3(4,8,1),   T, 0, stream>>>(pw2, pw2T, 128, 0, 0, 0, 256);
  transpose_w<<<dim3(4,8,1),   T, 0, stream>>>(dw2, dw2T, 128, 0, 0, 0, 256);
  concat2<<<dim3(4,4), T, 0, stream>>>(bkvb, 1024, bk, 512, 512, bv, 512, 512);
  concat2<<<dim3(2,1), T, 0, stream>>>(pd1b, 512, pb1, 256, 256, db1, 256, 256);
  f32_to_bf16_k<<<dim3(1024), T, 0, stream>>>(enc, mem16, 2048ll*512);
  init_q<<<dim3(12288), T, 0, stream>>>(vw, kp, q16);
  init_q96<<<dim3(24), T, 0, stream>>>(vw, kp, q96);

  // ---- 4 cross-attention layers ----
  for (int l = 0; l < 4; ++l) {
    // K/V projection FIRST (fused-attn epilogue of the Wq GEMM reads kv16)
    gemm_bt<0><<<dim3(8,16),  T, 0, stream>>>(mem16, 512, kvT + l*524288, bkvb + l*1024,
                                              kv16, 1024, 512, nullptr);
    if (l == 0) {
      // layer 0: 96 distinct q rows -> tiny Q-projection + broadcast attention
      gemm_bt<0><<<dim3(4,1), T, 0, stream>>>(q96, 512, wqT, bq, qh96, 512, 512, nullptr);
      attn_k<<<dim3(12288), T, 0, stream>>>(qh96, 96, kv16, bufQH);
    } else {
      // layers 1-3: Wq GEMM with FUSED attention epilogue -> bufQH = attn output
      gemm_bt<3><<<dim3(4,384), T, 0, stream>>>(q16, 512, wqT + l*262144, bq + l*512,
                                                bufQH, 512, 512, kv16);
    }
    // Wo with fused residual: q16 <- q16 + attn@Wo + bo  (in place, tile-local)
    gemm_bt<2><<<dim3(4,384), T, 0, stream>>>(bufQH, 512, woT + l*262144, bo + l*512,
                                              q16, 512, 512, q16);
    ln_only<<<dim3(12288), T, 0, stream>>>(q16, ln1g + l*512, ln1b + l*512);
    for (int c = 0; c < nCh; ++c) {   // FFN chunks (1 chunk if workspace allows)
      bf16* qc = q16 + (long)c*chunkRows*512;
      gemm_bt<1><<<dim3(16, chunkRows>>7), T, 0, stream>>>(qc, 512,
                                                w1T + l*1048576, fb1 + l*2048, bufF1, 2048, 512, nullptr);
      gemm_bt<2><<<dim3(4, chunkRows>>7),  T, 0, stream>>>(bufF1, 2048,
                                                w2T + l*1048576, fb2 + l*512,
                                                qc, 512, 2048, qc);
      ln_only<<<dim3(chunkRows>>2), T, 0, stream>>>(qc, ln2g + l*512, ln2b + l*512);
    }
  }

  // ---- heads ----
  gemm_bt<1><<<dim3(4,384), T, 0, stream>>>(q16, 512, pd1T, pd1b, bufQH, 512, 512, nullptr);
  gemm_bt<1><<<dim3(1,384), T, 0, stream>>>(bufQH, 512, pw2T, pb2, bufF1, 256, 256, nullptr);
  gemm_bt<1><<<dim3(1,384), T, 0, stream>>>(bufQH + 256, 512, dw2T, db2, bufF1 + 128, 256, 256, nullptr);
  finalize_k<<<dim3(12288), T, 0, stream>>>(q16, bufF1, cw, cb, pw3, pb3, dw3, db3,
                                            occ, okp, (float*)d_out);
}